// Round 4
// baseline (191.273 us; speedup 1.0000x reference)
//
#include <hip/hip_runtime.h>
#include <math.h>

#define NN 8
#define CC 20
#define PP 8732
#define MM 16
#define NPR 3
#define ROWS (NN * CC)
#define FBLK 1024
#define EPT 9   // ceil(PP / FBLK)

__device__ __forceinline__ float fast_rcp(float x) { return __builtin_amdgcn_rcpf(x); }
__device__ __forceinline__ float rfl(float x) {   // force wave-uniform value into SGPR
    return __uint_as_float(__builtin_amdgcn_readfirstlane(__float_as_uint(x)));
}

// fast lse over 2 logits: mx + log(1 + exp(-|a-b|)); single definition used
// everywhere so recomputed terms cancel bit-exactly.
__device__ __forceinline__ float lse2(float a, float b) {
    float mx = fmaxf(a, b);
    float d  = fabsf(a - b);
    return mx + __logf(1.0f + __expf(-d));
}

// ---------------- Fused kernel: one block per (image,class) row ----------------
// Round-3 root cause: 80 uniform box values overflowed the SGPR file into
// VGPRs -> demand > 64-VGPR cap -> 134 MB scratch traffic in the hot loop.
// Fix: TWO passes of 8 boxes over the priors. Per-pass uniform set = 40
// values (fits SGPRs); per-thread regs = bovk[9] + bestk8[8] + prior temps
// (~40 VGPR) -> no spill at the compiler's default 8-waves/EU target.
// Priors are re-read per pass (L2-resident, 140 KB); scores read once in the
// dedicated pos/ce pass. All packing/formulas identical to round 3.
__global__ __launch_bounds__(FBLK) void mbox_fused(
    const float* __restrict__ locs, const float* __restrict__ scores,
    const float* __restrict__ boxes, const int* __restrict__ labels,
    const float* __restrict__ priors, float* __restrict__ rstats)
{
    const int row = blockIdx.x, tid = threadIdx.x, lane = tid & 63, wav = tid >> 6;

    __shared__ float s_cef[PP];                         // per-prior ce bit pattern (as float)
    __shared__ unsigned char s_pkb[PP];                 // per-prior: pos<<4 | bm
    __shared__ unsigned long long s_pk64[16 * MM];      // per-wave per-object argmax keys
    __shared__ float s_bcx[MM], s_bcy[MM], s_bw[MM], s_bh[MM];
    __shared__ float s_rf[16 * 3];
    __shared__ int s_lab[MM], s_pfo[MM];
    __shared__ unsigned int s_hist[256];
    __shared__ unsigned int s_prefix, s_Kr, s_K;
    __shared__ float s_redf[16];
    __shared__ int s_redi[16];

    const float* bb = boxes + (size_t)row * MM * 4;
    unsigned int labm = 0;
    {
        const int* lb = labels + (size_t)row * MM;
#pragma unroll
        for (int m = 0; m < MM; m++) labm |= (lb[m] != 0 ? 1u : 0u) << m;
        labm = __builtin_amdgcn_readfirstlane(labm);
    }
    if (tid < MM) {
        const float* b = bb + tid * 4;
        float x1 = b[0], y1 = b[1], x2 = b[2], y2 = b[3];
        s_bcx[tid] = (x1 + x2) * 0.5f;
        s_bcy[tid] = (y1 + y2) * 0.5f;
        s_bw[tid]  = x2 - x1;
        s_bh[tid]  = y2 - y1;
        s_lab[tid] = labels[row * MM + tid];
    }
    __syncthreads();

    const float4* pri4 = (const float4*)priors;
    const float4* loc4 = (const float4*)(locs + (size_t)row * PP * 4);
    const float2* sc2  = (const float2*)(scores + (size_t)row * PP * 2);

    // bovk[k]: (iou_bits & ~15) | (15-m); u32-max == (max trunc-iou, min m).
    // Carried across the two 8-box passes in registers (9 VGPR).
    unsigned int bovk[EPT];
#pragma unroll
    for (int k = 0; k < EPT; k++) bovk[k] = 0u;

#pragma unroll
    for (int half = 0; half < 2; half++) {
        const int m0 = half * 8;
        // 8 boxes -> 40 wave-uniform values (fits SGPR file alongside bases)
        float x1[8], y1[8], x2[8], y2[8], ar[8];
#pragma unroll
        for (int m = 0; m < 8; m++) {
            float a1 = rfl(bb[(m0 + m) * 4 + 0]), b1 = rfl(bb[(m0 + m) * 4 + 1]);
            float a2 = rfl(bb[(m0 + m) * 4 + 2]), b2 = rfl(bb[(m0 + m) * 4 + 3]);
            x1[m] = a1; y1[m] = b1; x2[m] = a2; y2[m] = b2;
            ar[m] = rfl((a2 - a1) * (b2 - b1));
        }
        // bestk8[m]: (iou_bits & ~0xF) | (8-k); u32-max == (max trunc4-iou, min k == min p)
        unsigned int bestk8[8];
#pragma unroll
        for (int m = 0; m < 8; m++) bestk8[m] = 0u;

#pragma unroll
        for (int k = 0; k < EPT; k++) {
            const int p = tid + k * FBLK;
            if (p >= PP) continue;                   // only k==8 tail threads
            float4 pr = pri4[p];
            const unsigned int lowb = (unsigned int)(8 - k);
            float hw = pr.z * 0.5f, hh = pr.w * 0.5f;
            float px1 = pr.x - hw, py1 = pr.y - hh;
            float px2 = pr.x + hw, py2 = pr.y + hh;
            float area_b = (px2 - px1) * (py2 - py1);
            unsigned int bv = bovk[k];
#pragma unroll
            for (int m = 0; m < 8; m++) {
                float dx = fminf(x2[m], px2) - fmaxf(x1[m], px1);
                float dy = fminf(y2[m], py2) - fmaxf(y1[m], py1);
                dx = fmaxf(dx, 0.0f); dy = fmaxf(dy, 0.0f);
                float inter = dx * dy;
                float den = (ar[m] + area_b) - inter;
                float iou = inter * fast_rcp(den);
                unsigned int ib = __float_as_uint(iou);
                bv         = max(bv,         (ib & 0xFFFFFFF0u) | (unsigned int)(15 - (m0 + m)));
                bestk8[m]  = max(bestk8[m],  (ib & 0xFFFFFFF0u) | lowb);
            }
            bovk[k] = bv;
        }

        // per-object argmax: expand winner to exact-p u64 key, wave reduce
#pragma unroll
        for (int m = 0; m < 8; m++) {
            unsigned int bk = bestk8[m];
            int kk = 8 - (int)(bk & 0xFu);
            int pb = tid + kk * FBLK;
            unsigned long long key = ((unsigned long long)(bk & 0xFFFFFFF0u) << 32)
                                   | (unsigned int)(0x7fffffff - pb);
#pragma unroll
            for (int off = 32; off; off >>= 1) {
                unsigned long long o = __shfl_down(key, off);
                if (o > key) key = o;
            }
            if (lane == 0) s_pk64[wav * MM + m0 + m] = key;
        }
        // keep the two halves' box SGPR sets from being co-hoisted
        __builtin_amdgcn_sched_barrier(0);
    }

    // pos/ce pass: scores read exactly once; priors/locs only on rare pos path
    float l_np = 0.0f, l_l1 = 0.0f, l_cp = 0.0f;
#pragma unroll
    for (int k = 0; k < EPT; k++) {
        const int p = tid + k * FBLK;
        if (p >= PP) continue;
        unsigned int bv = bovk[k];
        int bm = 15 - (int)(bv & 15u);
        bool pos = (bv >= 0x3F000000u) && (((labm >> bm) & 1u) != 0u);
        s_pkb[p] = (unsigned char)((pos ? 16u : 0u) | (unsigned)bm);
        float2 sc = sc2[p];
        float lse = lse2(sc.x, sc.y);
        if (pos) {      // rare, divergent cold path
            float4 pr = pri4[p];
            float4 pl = loc4[p];
            l_np += 1.0f;
            l_cp += lse - sc.y;
            float tx = (s_bcx[bm] - pr.x) * 10.0f / pr.z;
            float ty = (s_bcy[bm] - pr.y) * 10.0f / pr.w;
            float tw = __logf(s_bw[bm] / pr.z) * 5.0f;
            float th = __logf(s_bh[bm] / pr.w) * 5.0f;
            l_l1 += fabsf(pl.x - tx) + fabsf(pl.y - ty) + fabsf(pl.z - tw) + fabsf(pl.w - th);
            s_cef[p] = 0.0f;
        } else {
            s_cef[p] = fmaxf(lse - sc.x, 0.0f);
        }
    }

#pragma unroll
    for (int off = 32; off; off >>= 1) {
        l_np += __shfl_down(l_np, off);
        l_l1 += __shfl_down(l_l1, off);
        l_cp += __shfl_down(l_cp, off);
    }
    if (lane == 0) { s_rf[wav * 3] = l_np; s_rf[wav * 3 + 1] = l_l1; s_rf[wav * 3 + 2] = l_cp; }
    __syncthreads();

    if (tid < MM) {
        unsigned long long key = s_pk64[tid];
        for (int w = 1; w < 16; w++) {
            unsigned long long o = s_pk64[w * MM + tid];
            if (o > key) key = o;
        }
        s_pfo[tid] = 0x7fffffff - (int)(unsigned)(key & 0xffffffffull);
    }
    __syncthreads();

    // force deltas (sequential last-wins == group by prior, keep largest m);
    // patches s_cef[p] in place, covered by the next __syncthreads.
    float d_np = 0, d_l1 = 0, d_cp = 0;
    if (tid < MM) {
        int p = s_pfo[tid];
        bool is_last = true;
        for (int mm = tid + 1; mm < MM; mm++) if (s_pfo[mm] == p) is_last = false;
        if (is_last) {
            const float4 pr = ((const float4*)priors)[p];
            const float4 pl = loc4[p];
            const float2 sc = sc2[p];
            float lse = lse2(sc.x, sc.y);
            unsigned int u = s_pkb[p];
            if (u & 16u) {   // remove old positive contribution
                int mo = u & 15;
                d_np -= 1.0f; d_cp -= (lse - sc.y);
                float tx = (s_bcx[mo] - pr.x) * 10.0f / pr.z;
                float ty = (s_bcy[mo] - pr.y) * 10.0f / pr.w;
                float tw = __logf(s_bw[mo] / pr.z) * 5.0f;
                float th = __logf(s_bh[mo] / pr.w) * 5.0f;
                d_l1 -= fabsf(pl.x - tx) + fabsf(pl.y - ty) + fabsf(pl.z - tw) + fabsf(pl.w - th);
            }
            if (s_lab[tid] != 0) {   // add forced positive (ov=1, m=tid)
                d_np += 1.0f; d_cp += (lse - sc.y);
                float tx = (s_bcx[tid] - pr.x) * 10.0f / pr.z;
                float ty = (s_bcy[tid] - pr.y) * 10.0f / pr.w;
                float tw = __logf(s_bw[tid] / pr.z) * 5.0f;
                float th = __logf(s_bh[tid] / pr.w) * 5.0f;
                d_l1 += fabsf(pl.x - tx) + fabsf(pl.y - ty) + fabsf(pl.z - tw) + fabsf(pl.w - th);
                s_cef[p] = 0.0f;                           // forced positive -> ce 0
            } else {
                s_cef[p] = fmaxf(lse - sc.x, 0.0f);        // forced but label 0 -> negative ce
            }
        }
    }
    if (tid < 64) {
#pragma unroll
        for (int off = 32; off; off >>= 1) {
            d_np += __shfl_down(d_np, off);
            d_l1 += __shfl_down(d_l1, off);
            d_cp += __shfl_down(d_cp, off);
        }
        if (tid == 0) {
            float np0 = 0, l10 = 0, cp0 = 0;
            for (int w = 0; w < 16; w++) {
                np0 += s_rf[w * 3]; l10 += s_rf[w * 3 + 1]; cp0 += s_rf[w * 3 + 2];
            }
            float np = np0 + d_np;
            rstats[(size_t)row * 8 + 0] = np;
            rstats[(size_t)row * 8 + 1] = l10 + d_l1;
            rstats[(size_t)row * 8 + 2] = cp0 + d_cp;
            int K = NPR * (int)(np + 0.5f);
            s_K = (K > 0) ? (unsigned)K : 0u;
            s_prefix = 0u;
            s_Kr = (K > 0) ? (unsigned)K : 0u;
        }
    }
    __syncthreads();

    // 4-pass 256-bin histogram radix select for the K-th largest bit pattern
    const unsigned int K = s_K;
    unsigned int T = 0u;
    if (K > 0u && K < PP) {
        for (int pass = 0; pass < 4; pass++) {
            const int shift = 24 - 8 * pass;
            if (tid < 256) s_hist[tid] = 0u;
            __syncthreads();
            const unsigned int pref   = s_prefix;
            const unsigned int maskhi = (pass == 0) ? 0u : (0xffffffffu << (shift + 8));
#pragma unroll
            for (int k = 0; k < EPT; k++) {
                const int p = tid + k * FBLK;
                unsigned int u = (p < PP) ? __float_as_uint(s_cef[p]) : 0u;
                if ((u & maskhi) == pref) atomicAdd(&s_hist[(u >> shift) & 255u], 1u);
            }
            __syncthreads();
            if (wav == 0) {
                unsigned int Kr = s_Kr;
                unsigned int h0 = s_hist[lane * 4 + 0];
                unsigned int h1 = s_hist[lane * 4 + 1];
                unsigned int h2 = s_hist[lane * 4 + 2];
                unsigned int h3 = s_hist[lane * 4 + 3];
                unsigned int c3 = h3;
                unsigned int c2 = h3 + h2;
                unsigned int c1 = c2 + h1;
                unsigned int c0 = c1 + h0;
                unsigned int suf = c0;
#pragma unroll
                for (int off = 1; off < 64; off <<= 1) {
                    unsigned int o = __shfl_down(suf, off);
                    if (lane + off < 64) suf += o;
                }
                unsigned int above = suf - c0;
                int cand = -1;
                unsigned int G = 0;
                if      (c3 + above >= Kr) { cand = lane * 4 + 3; G = above + c3 - h3; }
                else if (c2 + above >= Kr) { cand = lane * 4 + 2; G = above + c2 - h2; }
                else if (c1 + above >= Kr) { cand = lane * 4 + 1; G = above + c1 - h1; }
                else if (c0 + above >= Kr) { cand = lane * 4 + 0; G = above + c0 - h0; }
                int best = cand;
#pragma unroll
                for (int off = 32; off; off >>= 1) best = max(best, __shfl_down(best, off));
                best = __shfl(best, 0);
                if (cand == best && cand >= 0) {
                    s_Kr = Kr - G;
                    s_prefix = pref | ((unsigned int)best << shift);
                }
            }
            __syncthreads();
        }
        T = s_prefix;
    }

    // sum strictly greater than pivot + ties * pivot
    float sgt = 0.0f; int cgt = 0;
    if (K > 0u) {
#pragma unroll
        for (int k = 0; k < EPT; k++) {
            const int p = tid + k * FBLK;
            unsigned int u = (p < PP) ? __float_as_uint(s_cef[p]) : 0u;
            if (u > T) { sgt += __uint_as_float(u); cgt++; }
        }
    }
#pragma unroll
    for (int off = 32; off; off >>= 1) {
        sgt += __shfl_down(sgt, off);
        cgt += __shfl_down(cgt, off);
    }
    if (lane == 0) { s_redf[wav] = sgt; s_redi[wav] = cgt; }
    __syncthreads();
    if (tid == 0) {
        float s = 0; int cnt = 0;
        for (int w = 0; w < 16; w++) { s += s_redf[w]; cnt += s_redi[w]; }
        float chard = (K > 0u) ? (s + (float)(int)(K - (unsigned)cnt) * __uint_as_float(T)) : 0.0f;
        rstats[(size_t)row * 8 + 4] = chard;
    }
}

// ---------------- Final cross-row reduction ----------------
__global__ void mbox_finalize(const float* __restrict__ rstats, float* __restrict__ out) {
    int c = threadIdx.x;
    float loss = 0.0f;
    if (c < CC) {
        float np = 0, l1 = 0, cp = 0, ch = 0;
        for (int n = 0; n < NN; n++) {
            const float* s = rstats + ((size_t)(n * CC + c)) * 8;
            np += s[0]; l1 += s[1]; cp += s[2]; ch += s[4];
        }
        float loc = l1 / fmaxf(np * 4.0f, 1.0f);
        float val = (np > 0.0f) ? (cp + ch + loc) / fmaxf(np, 1.0f) : 0.0f;
        loss = val / (float)CC;
    }
#pragma unroll
    for (int off = 32; off; off >>= 1) loss += __shfl_down(loss, off);
    if (threadIdx.x == 0) out[0] = loss;
}

extern "C" void kernel_launch(void* const* d_in, const int* in_sizes, int n_in,
                              void* d_out, int out_size, void* d_ws, size_t ws_size,
                              hipStream_t stream) {
    const float* locs   = (const float*)d_in[0];
    const float* scores = (const float*)d_in[1];
    const float* boxes  = (const float*)d_in[2];
    const int*   labels = (const int*)d_in[3];
    const float* priors = (const float*)d_in[4];
    float* out = (float*)d_out;

    float* rstats = (float*)d_ws;   // 160 rows * 8 floats = 5,120 B

    mbox_fused<<<ROWS, FBLK, 0, stream>>>(locs, scores, boxes, labels, priors, rstats);
    mbox_finalize<<<1, 64, 0, stream>>>(rstats, out);
}

// Round 5
// 139.519 us; speedup vs baseline: 1.3709x; 1.3709x over previous
//
#include <hip/hip_runtime.h>
#include <math.h>

#define NN 8
#define CC 20
#define PP 8732
#define MM 16
#define NPR 3
#define ROWS (NN * CC)
#define FBLK 1024
#define EPT 9   // ceil(PP / FBLK)

__device__ __forceinline__ float fast_rcp(float x) { return __builtin_amdgcn_rcpf(x); }
__device__ __forceinline__ float rfl(float x) {   // force wave-uniform value into SGPR
    return __uint_as_float(__builtin_amdgcn_readfirstlane(__float_as_uint(x)));
}

// fast lse over 2 logits: mx + log(1 + exp(-|a-b|)); single definition used
// everywhere so recomputed terms cancel bit-exactly.
__device__ __forceinline__ float lse2(float a, float b) {
    float mx = fmaxf(a, b);
    float d  = fabsf(a - b);
    return mx + __logf(1.0f + __expf(-d));
}

// ---------------- Fused kernel: one block per (image,class) row ----------------
// Round-4 root cause: with a 1024-thread workgroup the backend targets
// 8 waves/EU -> 64-VGPR budget -> per-thread arrays (bovk/bestk) DEMOTED to
// scratch; every update became a scratch RMW (141 MB writes, VALUBusy 14%).
// Fix: (1) amdgpu_waves_per_eu(4,4): grid=160 <= 256 CUs means >1 wg/CU is
// worthless, so pin 4 waves/EU -> 128-VGPR budget. (2) bovk state moved to
// LDS (s_u32, later reused for ce bit patterns; each thread owns its p, so
// no sync needed) -> hot-loop register demand ~30 VGPR, fits any budget.
__attribute__((amdgpu_waves_per_eu(4, 4)))
__global__ __launch_bounds__(FBLK) void mbox_fused(
    const float* __restrict__ locs, const float* __restrict__ scores,
    const float* __restrict__ boxes, const int* __restrict__ labels,
    const float* __restrict__ priors, float* __restrict__ rstats)
{
    const int row = blockIdx.x, tid = threadIdx.x, lane = tid & 63, wav = tid >> 6;

    // s_u32[p]: matching phase = packed bovk key ((iou&~15)|(15-m));
    //           after pos/ce phase = ce bit pattern (float as uint).
    __shared__ unsigned int s_u32[PP];
    __shared__ unsigned char s_pkb[PP];                 // per-prior: pos<<4 | bm
    __shared__ unsigned long long s_pk64[16 * MM];      // per-wave per-object argmax keys
    __shared__ float s_bcx[MM], s_bcy[MM], s_bw[MM], s_bh[MM];
    __shared__ float s_rf[16 * 3];
    __shared__ int s_lab[MM], s_pfo[MM];
    __shared__ unsigned int s_hist[256];
    __shared__ unsigned int s_prefix, s_Kr, s_K;
    __shared__ float s_redf[16];
    __shared__ int s_redi[16];

    const float* bb = boxes + (size_t)row * MM * 4;
    unsigned int labm = 0;
    {
        const int* lb = labels + (size_t)row * MM;
#pragma unroll
        for (int m = 0; m < MM; m++) labm |= (lb[m] != 0 ? 1u : 0u) << m;
        labm = __builtin_amdgcn_readfirstlane(labm);
    }
    if (tid < MM) {
        const float* b = bb + tid * 4;
        float x1 = b[0], y1 = b[1], x2 = b[2], y2 = b[3];
        s_bcx[tid] = (x1 + x2) * 0.5f;
        s_bcy[tid] = (y1 + y2) * 0.5f;
        s_bw[tid]  = x2 - x1;
        s_bh[tid]  = y2 - y1;
        s_lab[tid] = labels[row * MM + tid];
    }
    __syncthreads();

    const float4* pri4 = (const float4*)priors;
    const float4* loc4 = (const float4*)(locs + (size_t)row * PP * 4);
    const float2* sc2  = (const float2*)(scores + (size_t)row * PP * 2);

    // ---- matching: two passes of 8 boxes (40 uniform values fit SGPRs) ----
#pragma unroll
    for (int half = 0; half < 2; half++) {
        const int m0 = half * 8;
        float x1[8], y1[8], x2[8], y2[8], ar[8];
#pragma unroll
        for (int m = 0; m < 8; m++) {
            float a1 = rfl(bb[(m0 + m) * 4 + 0]), b1 = rfl(bb[(m0 + m) * 4 + 1]);
            float a2 = rfl(bb[(m0 + m) * 4 + 2]), b2 = rfl(bb[(m0 + m) * 4 + 3]);
            x1[m] = a1; y1[m] = b1; x2[m] = a2; y2[m] = b2;
            ar[m] = rfl((a2 - a1) * (b2 - b1));
        }
        // bestk8[m]: (iou_bits & ~0xF) | (8-k); u32-max == (max trunc4-iou, min k == min p)
        unsigned int bestk8[8];
#pragma unroll
        for (int m = 0; m < 8; m++) bestk8[m] = 0u;

#pragma unroll
        for (int k = 0; k < EPT; k++) {
            const int p = tid + k * FBLK;
            if (p >= PP) continue;                   // only k==8 tail threads
            float4 pr = pri4[p];
            const unsigned int lowb = (unsigned int)(8 - k);
            float hw = pr.z * 0.5f, hh = pr.w * 0.5f;
            float px1 = pr.x - hw, py1 = pr.y - hh;
            float px2 = pr.x + hw, py2 = pr.y + hh;
            float area_b = (px2 - px1) * (py2 - py1);
            unsigned int bv = (half == 0) ? 0u : s_u32[p];   // thread-private slot
#pragma unroll
            for (int m = 0; m < 8; m++) {
                float dx = fminf(x2[m], px2) - fmaxf(x1[m], px1);
                float dy = fminf(y2[m], py2) - fmaxf(y1[m], py1);
                dx = fmaxf(dx, 0.0f); dy = fmaxf(dy, 0.0f);
                float inter = dx * dy;
                float den = (ar[m] + area_b) - inter;
                float iou = inter * fast_rcp(den);
                unsigned int ib = __float_as_uint(iou);
                bv        = max(bv,        (ib & 0xFFFFFFF0u) | (unsigned int)(15 - (m0 + m)));
                bestk8[m] = max(bestk8[m], (ib & 0xFFFFFFF0u) | lowb);
            }
            s_u32[p] = bv;
        }

        // per-object argmax: expand winner to exact-p u64 key, wave reduce
#pragma unroll
        for (int m = 0; m < 8; m++) {
            unsigned int bk = bestk8[m];
            int kk = 8 - (int)(bk & 0xFu);
            int pb = tid + kk * FBLK;
            unsigned long long key = ((unsigned long long)(bk & 0xFFFFFFF0u) << 32)
                                   | (unsigned int)(0x7fffffff - pb);
#pragma unroll
            for (int off = 32; off; off >>= 1) {
                unsigned long long o = __shfl_down(key, off);
                if (o > key) key = o;
            }
            if (lane == 0) s_pk64[wav * MM + m0 + m] = key;
        }
        // keep the two halves' box SGPR sets from being co-hoisted
        __builtin_amdgcn_sched_barrier(0);
    }

    // ---- pos/ce pass: scores read exactly once; s_u32 bovk -> ce in place ----
    float l_np = 0.0f, l_l1 = 0.0f, l_cp = 0.0f;
#pragma unroll
    for (int k = 0; k < EPT; k++) {
        const int p = tid + k * FBLK;
        if (p >= PP) continue;
        unsigned int bv = s_u32[p];
        int bm = 15 - (int)(bv & 15u);
        bool pos = (bv >= 0x3F000000u) && (((labm >> bm) & 1u) != 0u);
        s_pkb[p] = (unsigned char)((pos ? 16u : 0u) | (unsigned)bm);
        float2 sc = sc2[p];
        float lse = lse2(sc.x, sc.y);
        if (pos) {      // rare, divergent cold path
            float4 pr = pri4[p];
            float4 pl = loc4[p];
            l_np += 1.0f;
            l_cp += lse - sc.y;
            float tx = (s_bcx[bm] - pr.x) * 10.0f / pr.z;
            float ty = (s_bcy[bm] - pr.y) * 10.0f / pr.w;
            float tw = __logf(s_bw[bm] / pr.z) * 5.0f;
            float th = __logf(s_bh[bm] / pr.w) * 5.0f;
            l_l1 += fabsf(pl.x - tx) + fabsf(pl.y - ty) + fabsf(pl.z - tw) + fabsf(pl.w - th);
            s_u32[p] = 0u;                               // ce = 0.0f
        } else {
            s_u32[p] = __float_as_uint(fmaxf(lse - sc.x, 0.0f));
        }
    }

#pragma unroll
    for (int off = 32; off; off >>= 1) {
        l_np += __shfl_down(l_np, off);
        l_l1 += __shfl_down(l_l1, off);
        l_cp += __shfl_down(l_cp, off);
    }
    if (lane == 0) { s_rf[wav * 3] = l_np; s_rf[wav * 3 + 1] = l_l1; s_rf[wav * 3 + 2] = l_cp; }
    __syncthreads();

    if (tid < MM) {
        unsigned long long key = s_pk64[tid];
        for (int w = 1; w < 16; w++) {
            unsigned long long o = s_pk64[w * MM + tid];
            if (o > key) key = o;
        }
        s_pfo[tid] = 0x7fffffff - (int)(unsigned)(key & 0xffffffffull);
    }
    __syncthreads();

    // force deltas (sequential last-wins == group by prior, keep largest m);
    // patches s_u32[p] (ce bits) in place, covered by the next __syncthreads.
    float d_np = 0, d_l1 = 0, d_cp = 0;
    if (tid < MM) {
        int p = s_pfo[tid];
        bool is_last = true;
        for (int mm = tid + 1; mm < MM; mm++) if (s_pfo[mm] == p) is_last = false;
        if (is_last) {
            const float4 pr = ((const float4*)priors)[p];
            const float4 pl = loc4[p];
            const float2 sc = sc2[p];
            float lse = lse2(sc.x, sc.y);
            unsigned int u = s_pkb[p];
            if (u & 16u) {   // remove old positive contribution
                int mo = u & 15;
                d_np -= 1.0f; d_cp -= (lse - sc.y);
                float tx = (s_bcx[mo] - pr.x) * 10.0f / pr.z;
                float ty = (s_bcy[mo] - pr.y) * 10.0f / pr.w;
                float tw = __logf(s_bw[mo] / pr.z) * 5.0f;
                float th = __logf(s_bh[mo] / pr.w) * 5.0f;
                d_l1 -= fabsf(pl.x - tx) + fabsf(pl.y - ty) + fabsf(pl.z - tw) + fabsf(pl.w - th);
            }
            if (s_lab[tid] != 0) {   // add forced positive (ov=1, m=tid)
                d_np += 1.0f; d_cp += (lse - sc.y);
                float tx = (s_bcx[tid] - pr.x) * 10.0f / pr.z;
                float ty = (s_bcy[tid] - pr.y) * 10.0f / pr.w;
                float tw = __logf(s_bw[tid] / pr.z) * 5.0f;
                float th = __logf(s_bh[tid] / pr.w) * 5.0f;
                d_l1 += fabsf(pl.x - tx) + fabsf(pl.y - ty) + fabsf(pl.z - tw) + fabsf(pl.w - th);
                s_u32[p] = 0u;                             // forced positive -> ce 0
            } else {
                s_u32[p] = __float_as_uint(fmaxf(lse - sc.x, 0.0f)); // forced, label 0
            }
        }
    }
    if (tid < 64) {
#pragma unroll
        for (int off = 32; off; off >>= 1) {
            d_np += __shfl_down(d_np, off);
            d_l1 += __shfl_down(d_l1, off);
            d_cp += __shfl_down(d_cp, off);
        }
        if (tid == 0) {
            float np0 = 0, l10 = 0, cp0 = 0;
            for (int w = 0; w < 16; w++) {
                np0 += s_rf[w * 3]; l10 += s_rf[w * 3 + 1]; cp0 += s_rf[w * 3 + 2];
            }
            float np = np0 + d_np;
            rstats[(size_t)row * 8 + 0] = np;
            rstats[(size_t)row * 8 + 1] = l10 + d_l1;
            rstats[(size_t)row * 8 + 2] = cp0 + d_cp;
            int K = NPR * (int)(np + 0.5f);
            s_K = (K > 0) ? (unsigned)K : 0u;
            s_prefix = 0u;
            s_Kr = (K > 0) ? (unsigned)K : 0u;
        }
    }
    __syncthreads();

    // 4-pass 256-bin histogram radix select for the K-th largest bit pattern
    const unsigned int K = s_K;
    unsigned int T = 0u;
    if (K > 0u && K < PP) {
        for (int pass = 0; pass < 4; pass++) {
            const int shift = 24 - 8 * pass;
            if (tid < 256) s_hist[tid] = 0u;
            __syncthreads();
            const unsigned int pref   = s_prefix;
            const unsigned int maskhi = (pass == 0) ? 0u : (0xffffffffu << (shift + 8));
#pragma unroll
            for (int k = 0; k < EPT; k++) {
                const int p = tid + k * FBLK;
                unsigned int u = (p < PP) ? s_u32[p] : 0u;
                if ((u & maskhi) == pref) atomicAdd(&s_hist[(u >> shift) & 255u], 1u);
            }
            __syncthreads();
            if (wav == 0) {
                unsigned int Kr = s_Kr;
                unsigned int h0 = s_hist[lane * 4 + 0];
                unsigned int h1 = s_hist[lane * 4 + 1];
                unsigned int h2 = s_hist[lane * 4 + 2];
                unsigned int h3 = s_hist[lane * 4 + 3];
                unsigned int c3 = h3;
                unsigned int c2 = h3 + h2;
                unsigned int c1 = c2 + h1;
                unsigned int c0 = c1 + h0;
                unsigned int suf = c0;
#pragma unroll
                for (int off = 1; off < 64; off <<= 1) {
                    unsigned int o = __shfl_down(suf, off);
                    if (lane + off < 64) suf += o;
                }
                unsigned int above = suf - c0;
                int cand = -1;
                unsigned int G = 0;
                if      (c3 + above >= Kr) { cand = lane * 4 + 3; G = above + c3 - h3; }
                else if (c2 + above >= Kr) { cand = lane * 4 + 2; G = above + c2 - h2; }
                else if (c1 + above >= Kr) { cand = lane * 4 + 1; G = above + c1 - h1; }
                else if (c0 + above >= Kr) { cand = lane * 4 + 0; G = above + c0 - h0; }
                int best = cand;
#pragma unroll
                for (int off = 32; off; off >>= 1) best = max(best, __shfl_down(best, off));
                best = __shfl(best, 0);
                if (cand == best && cand >= 0) {
                    s_Kr = Kr - G;
                    s_prefix = pref | ((unsigned int)best << shift);
                }
            }
            __syncthreads();
        }
        T = s_prefix;
    }

    // sum strictly greater than pivot + ties * pivot
    float sgt = 0.0f; int cgt = 0;
    if (K > 0u) {
#pragma unroll
        for (int k = 0; k < EPT; k++) {
            const int p = tid + k * FBLK;
            unsigned int u = (p < PP) ? s_u32[p] : 0u;
            if (u > T) { sgt += __uint_as_float(u); cgt++; }
        }
    }
#pragma unroll
    for (int off = 32; off; off >>= 1) {
        sgt += __shfl_down(sgt, off);
        cgt += __shfl_down(cgt, off);
    }
    if (lane == 0) { s_redf[wav] = sgt; s_redi[wav] = cgt; }
    __syncthreads();
    if (tid == 0) {
        float s = 0; int cnt = 0;
        for (int w = 0; w < 16; w++) { s += s_redf[w]; cnt += s_redi[w]; }
        float chard = (K > 0u) ? (s + (float)(int)(K - (unsigned)cnt) * __uint_as_float(T)) : 0.0f;
        rstats[(size_t)row * 8 + 4] = chard;
    }
}

// ---------------- Final cross-row reduction ----------------
__global__ void mbox_finalize(const float* __restrict__ rstats, float* __restrict__ out) {
    int c = threadIdx.x;
    float loss = 0.0f;
    if (c < CC) {
        float np = 0, l1 = 0, cp = 0, ch = 0;
        for (int n = 0; n < NN; n++) {
            const float* s = rstats + ((size_t)(n * CC + c)) * 8;
            np += s[0]; l1 += s[1]; cp += s[2]; ch += s[4];
        }
        float loc = l1 / fmaxf(np * 4.0f, 1.0f);
        float val = (np > 0.0f) ? (cp + ch + loc) / fmaxf(np, 1.0f) : 0.0f;
        loss = val / (float)CC;
    }
#pragma unroll
    for (int off = 32; off; off >>= 1) loss += __shfl_down(loss, off);
    if (threadIdx.x == 0) out[0] = loss;
}

extern "C" void kernel_launch(void* const* d_in, const int* in_sizes, int n_in,
                              void* d_out, int out_size, void* d_ws, size_t ws_size,
                              hipStream_t stream) {
    const float* locs   = (const float*)d_in[0];
    const float* scores = (const float*)d_in[1];
    const float* boxes  = (const float*)d_in[2];
    const int*   labels = (const int*)d_in[3];
    const float* priors = (const float*)d_in[4];
    float* out = (float*)d_out;

    float* rstats = (float*)d_ws;   // 160 rows * 8 floats = 5,120 B

    mbox_fused<<<ROWS, FBLK, 0, stream>>>(locs, scores, boxes, labels, priors, rstats);
    mbox_finalize<<<1, 64, 0, stream>>>(rstats, out);
}

// Round 6
// 121.635 us; speedup vs baseline: 1.5725x; 1.1470x over previous
//
#include <hip/hip_runtime.h>
#include <math.h>

#define NN 8
#define CC 20
#define PP 8732
#define MM 16
#define NPR 3
#define ROWS (NN * CC)
#define FBLK 1024
#define EPT 9   // ceil(PP / FBLK)

__device__ __forceinline__ float fast_rcp(float x) { return __builtin_amdgcn_rcpf(x); }
__device__ __forceinline__ float rfl(float x) {   // force wave-uniform value into SGPR
    return __uint_as_float(__builtin_amdgcn_readfirstlane(__float_as_uint(x)));
}

// fast lse over 2 logits: mx + log(1 + exp(-|a-b|)); single definition used
// everywhere so recomputed terms cancel bit-exactly.
__device__ __forceinline__ float lse2(float a, float b) {
    float mx = fmaxf(a, b);
    float d  = fabsf(a - b);
    return mx + __logf(1.0f + __expf(-d));
}

// ---------------- Fused kernel: one block per (image,class) row ----------------
// Round-5 root cause (refined): 40 uniform box values/pass + arg pointers
// overflow the SGPR file; overflow lands in VGPRs, exceeds the 64-VGPR budget
// the backend picks for 1024-thread blocks, and the allocator DEMOTES the
// arrays to scratch (39 MB writes = 238 B/thread). waves_per_eu was ignored.
// Fix: FOUR passes of FOUR boxes. 20 uniform values/pass fit SGPRs; per-pass
// VGPR demand ~35 -> zero scratch at any budget. Per-prior argmax-m key
// lives in LDS (s_u32, thread-private slot, carried across passes; later
// reused for ce bit patterns). Priors re-read per pass (L2-resident).
__global__ __launch_bounds__(FBLK) void mbox_fused(
    const float* __restrict__ locs, const float* __restrict__ scores,
    const float* __restrict__ boxes, const int* __restrict__ labels,
    const float* __restrict__ priors, float* __restrict__ rstats)
{
    const int row = blockIdx.x, tid = threadIdx.x, lane = tid & 63, wav = tid >> 6;

    // s_u32[p]: matching phase = packed bovk key ((iou&~15)|(15-m));
    //           after pos/ce phase = ce bit pattern (float as uint).
    __shared__ unsigned int s_u32[PP];
    __shared__ unsigned char s_pkb[PP];                 // per-prior: pos<<4 | bm
    __shared__ unsigned long long s_pk64[16 * MM];      // per-wave per-object argmax keys
    __shared__ float s_bcx[MM], s_bcy[MM], s_bw[MM], s_bh[MM];
    __shared__ float s_rf[16 * 3];
    __shared__ int s_lab[MM], s_pfo[MM];
    __shared__ unsigned int s_hist[256];
    __shared__ unsigned int s_prefix, s_Kr, s_K;
    __shared__ float s_redf[16];
    __shared__ int s_redi[16];

    const float* bb = boxes + (size_t)row * MM * 4;
    unsigned int labm = 0;
    {
        const int* lb = labels + (size_t)row * MM;
#pragma unroll
        for (int m = 0; m < MM; m++) labm |= (lb[m] != 0 ? 1u : 0u) << m;
        labm = __builtin_amdgcn_readfirstlane(labm);
    }
    if (tid < MM) {
        const float* b = bb + tid * 4;
        float x1 = b[0], y1 = b[1], x2 = b[2], y2 = b[3];
        s_bcx[tid] = (x1 + x2) * 0.5f;
        s_bcy[tid] = (y1 + y2) * 0.5f;
        s_bw[tid]  = x2 - x1;
        s_bh[tid]  = y2 - y1;
        s_lab[tid] = labels[row * MM + tid];
    }
    __syncthreads();

    const float4* pri4 = (const float4*)priors;
    const float4* loc4 = (const float4*)(locs + (size_t)row * PP * 4);
    const float2* sc2  = (const float2*)(scores + (size_t)row * PP * 2);

    // ---- matching: four passes of 4 boxes (20 uniform values fit SGPRs) ----
#pragma unroll
    for (int pass4 = 0; pass4 < 4; pass4++) {
        const int m0 = pass4 * 4;
        float x1[4], y1[4], x2[4], y2[4], ar[4];
#pragma unroll
        for (int m = 0; m < 4; m++) {
            float a1 = rfl(bb[(m0 + m) * 4 + 0]), b1 = rfl(bb[(m0 + m) * 4 + 1]);
            float a2 = rfl(bb[(m0 + m) * 4 + 2]), b2 = rfl(bb[(m0 + m) * 4 + 3]);
            x1[m] = a1; y1[m] = b1; x2[m] = a2; y2[m] = b2;
            ar[m] = rfl((a2 - a1) * (b2 - b1));
        }
        // bestk4[m]: (iou_bits & ~0xF) | (8-k); u32-max == (max trunc4-iou, min k == min p)
        unsigned int bestk4[4];
#pragma unroll
        for (int m = 0; m < 4; m++) bestk4[m] = 0u;

#pragma unroll
        for (int k = 0; k < EPT; k++) {
            const int p = tid + k * FBLK;
            if (p >= PP) continue;                   // only k==8 tail threads
            float4 pr = pri4[p];
            const unsigned int lowb = (unsigned int)(8 - k);
            float hw = pr.z * 0.5f, hh = pr.w * 0.5f;
            float px1 = pr.x - hw, py1 = pr.y - hh;
            float px2 = pr.x + hw, py2 = pr.y + hh;
            float area_b = (px2 - px1) * (py2 - py1);
            unsigned int bv = (pass4 == 0) ? 0u : s_u32[p];   // thread-private slot
#pragma unroll
            for (int m = 0; m < 4; m++) {
                float dx = fminf(x2[m], px2) - fmaxf(x1[m], px1);
                float dy = fminf(y2[m], py2) - fmaxf(y1[m], py1);
                dx = fmaxf(dx, 0.0f); dy = fmaxf(dy, 0.0f);
                float inter = dx * dy;
                float den = (ar[m] + area_b) - inter;
                float iou = inter * fast_rcp(den);
                unsigned int ib = __float_as_uint(iou);
                bv        = max(bv,        (ib & 0xFFFFFFF0u) | (unsigned int)(15 - (m0 + m)));
                bestk4[m] = max(bestk4[m], (ib & 0xFFFFFFF0u) | lowb);
            }
            s_u32[p] = bv;
        }

        // per-object argmax: expand winner to exact-p u64 key, wave reduce
#pragma unroll
        for (int m = 0; m < 4; m++) {
            unsigned int bk = bestk4[m];
            int kk = 8 - (int)(bk & 0xFu);
            int pb = tid + kk * FBLK;
            unsigned long long key = ((unsigned long long)(bk & 0xFFFFFFF0u) << 32)
                                   | (unsigned int)(0x7fffffff - pb);
#pragma unroll
            for (int off = 32; off; off >>= 1) {
                unsigned long long o = __shfl_down(key, off);
                if (o > key) key = o;
            }
            if (lane == 0) s_pk64[wav * MM + m0 + m] = key;
        }
        // keep each pass's box SGPR set from being co-hoisted with the next
        __builtin_amdgcn_sched_barrier(0);
    }

    // ---- pos/ce pass: scores read exactly once; s_u32 bovk -> ce in place ----
    float l_np = 0.0f, l_l1 = 0.0f, l_cp = 0.0f;
#pragma unroll
    for (int k = 0; k < EPT; k++) {
        const int p = tid + k * FBLK;
        if (p >= PP) continue;
        unsigned int bv = s_u32[p];
        int bm = 15 - (int)(bv & 15u);
        bool pos = (bv >= 0x3F000000u) && (((labm >> bm) & 1u) != 0u);
        s_pkb[p] = (unsigned char)((pos ? 16u : 0u) | (unsigned)bm);
        float2 sc = sc2[p];
        float lse = lse2(sc.x, sc.y);
        if (pos) {      // rare, divergent cold path
            float4 pr = pri4[p];
            float4 pl = loc4[p];
            l_np += 1.0f;
            l_cp += lse - sc.y;
            float tx = (s_bcx[bm] - pr.x) * 10.0f / pr.z;
            float ty = (s_bcy[bm] - pr.y) * 10.0f / pr.w;
            float tw = __logf(s_bw[bm] / pr.z) * 5.0f;
            float th = __logf(s_bh[bm] / pr.w) * 5.0f;
            l_l1 += fabsf(pl.x - tx) + fabsf(pl.y - ty) + fabsf(pl.z - tw) + fabsf(pl.w - th);
            s_u32[p] = 0u;                               // ce = 0.0f
        } else {
            s_u32[p] = __float_as_uint(fmaxf(lse - sc.x, 0.0f));
        }
    }

#pragma unroll
    for (int off = 32; off; off >>= 1) {
        l_np += __shfl_down(l_np, off);
        l_l1 += __shfl_down(l_l1, off);
        l_cp += __shfl_down(l_cp, off);
    }
    if (lane == 0) { s_rf[wav * 3] = l_np; s_rf[wav * 3 + 1] = l_l1; s_rf[wav * 3 + 2] = l_cp; }
    __syncthreads();

    if (tid < MM) {
        unsigned long long key = s_pk64[tid];
        for (int w = 1; w < 16; w++) {
            unsigned long long o = s_pk64[w * MM + tid];
            if (o > key) key = o;
        }
        s_pfo[tid] = 0x7fffffff - (int)(unsigned)(key & 0xffffffffull);
    }
    __syncthreads();

    // force deltas (sequential last-wins == group by prior, keep largest m);
    // patches s_u32[p] (ce bits) in place, covered by the next __syncthreads.
    float d_np = 0, d_l1 = 0, d_cp = 0;
    if (tid < MM) {
        int p = s_pfo[tid];
        bool is_last = true;
        for (int mm = tid + 1; mm < MM; mm++) if (s_pfo[mm] == p) is_last = false;
        if (is_last) {
            const float4 pr = ((const float4*)priors)[p];
            const float4 pl = loc4[p];
            const float2 sc = sc2[p];
            float lse = lse2(sc.x, sc.y);
            unsigned int u = s_pkb[p];
            if (u & 16u) {   // remove old positive contribution
                int mo = u & 15;
                d_np -= 1.0f; d_cp -= (lse - sc.y);
                float tx = (s_bcx[mo] - pr.x) * 10.0f / pr.z;
                float ty = (s_bcy[mo] - pr.y) * 10.0f / pr.w;
                float tw = __logf(s_bw[mo] / pr.z) * 5.0f;
                float th = __logf(s_bh[mo] / pr.w) * 5.0f;
                d_l1 -= fabsf(pl.x - tx) + fabsf(pl.y - ty) + fabsf(pl.z - tw) + fabsf(pl.w - th);
            }
            if (s_lab[tid] != 0) {   // add forced positive (ov=1, m=tid)
                d_np += 1.0f; d_cp += (lse - sc.y);
                float tx = (s_bcx[tid] - pr.x) * 10.0f / pr.z;
                float ty = (s_bcy[tid] - pr.y) * 10.0f / pr.w;
                float tw = __logf(s_bw[tid] / pr.z) * 5.0f;
                float th = __logf(s_bh[tid] / pr.w) * 5.0f;
                d_l1 += fabsf(pl.x - tx) + fabsf(pl.y - ty) + fabsf(pl.z - tw) + fabsf(pl.w - th);
                s_u32[p] = 0u;                             // forced positive -> ce 0
            } else {
                s_u32[p] = __float_as_uint(fmaxf(lse - sc.x, 0.0f)); // forced, label 0
            }
        }
    }
    if (tid < 64) {
#pragma unroll
        for (int off = 32; off; off >>= 1) {
            d_np += __shfl_down(d_np, off);
            d_l1 += __shfl_down(d_l1, off);
            d_cp += __shfl_down(d_cp, off);
        }
        if (tid == 0) {
            float np0 = 0, l10 = 0, cp0 = 0;
            for (int w = 0; w < 16; w++) {
                np0 += s_rf[w * 3]; l10 += s_rf[w * 3 + 1]; cp0 += s_rf[w * 3 + 2];
            }
            float np = np0 + d_np;
            rstats[(size_t)row * 8 + 0] = np;
            rstats[(size_t)row * 8 + 1] = l10 + d_l1;
            rstats[(size_t)row * 8 + 2] = cp0 + d_cp;
            int K = NPR * (int)(np + 0.5f);
            s_K = (K > 0) ? (unsigned)K : 0u;
            s_prefix = 0u;
            s_Kr = (K > 0) ? (unsigned)K : 0u;
        }
    }
    __syncthreads();

    // 4-pass 256-bin histogram radix select for the K-th largest bit pattern
    const unsigned int K = s_K;
    unsigned int T = 0u;
    if (K > 0u && K < PP) {
        for (int pass = 0; pass < 4; pass++) {
            const int shift = 24 - 8 * pass;
            if (tid < 256) s_hist[tid] = 0u;
            __syncthreads();
            const unsigned int pref   = s_prefix;
            const unsigned int maskhi = (pass == 0) ? 0u : (0xffffffffu << (shift + 8));
#pragma unroll
            for (int k = 0; k < EPT; k++) {
                const int p = tid + k * FBLK;
                unsigned int u = (p < PP) ? s_u32[p] : 0u;
                if ((u & maskhi) == pref) atomicAdd(&s_hist[(u >> shift) & 255u], 1u);
            }
            __syncthreads();
            if (wav == 0) {
                unsigned int Kr = s_Kr;
                unsigned int h0 = s_hist[lane * 4 + 0];
                unsigned int h1 = s_hist[lane * 4 + 1];
                unsigned int h2 = s_hist[lane * 4 + 2];
                unsigned int h3 = s_hist[lane * 4 + 3];
                unsigned int c3 = h3;
                unsigned int c2 = h3 + h2;
                unsigned int c1 = c2 + h1;
                unsigned int c0 = c1 + h0;
                unsigned int suf = c0;
#pragma unroll
                for (int off = 1; off < 64; off <<= 1) {
                    unsigned int o = __shfl_down(suf, off);
                    if (lane + off < 64) suf += o;
                }
                unsigned int above = suf - c0;
                int cand = -1;
                unsigned int G = 0;
                if      (c3 + above >= Kr) { cand = lane * 4 + 3; G = above + c3 - h3; }
                else if (c2 + above >= Kr) { cand = lane * 4 + 2; G = above + c2 - h2; }
                else if (c1 + above >= Kr) { cand = lane * 4 + 1; G = above + c1 - h1; }
                else if (c0 + above >= Kr) { cand = lane * 4 + 0; G = above + c0 - h0; }
                int best = cand;
#pragma unroll
                for (int off = 32; off; off >>= 1) best = max(best, __shfl_down(best, off));
                best = __shfl(best, 0);
                if (cand == best && cand >= 0) {
                    s_Kr = Kr - G;
                    s_prefix = pref | ((unsigned int)best << shift);
                }
            }
            __syncthreads();
        }
        T = s_prefix;
    }

    // sum strictly greater than pivot + ties * pivot
    float sgt = 0.0f; int cgt = 0;
    if (K > 0u) {
#pragma unroll
        for (int k = 0; k < EPT; k++) {
            const int p = tid + k * FBLK;
            unsigned int u = (p < PP) ? s_u32[p] : 0u;
            if (u > T) { sgt += __uint_as_float(u); cgt++; }
        }
    }
#pragma unroll
    for (int off = 32; off; off >>= 1) {
        sgt += __shfl_down(sgt, off);
        cgt += __shfl_down(cgt, off);
    }
    if (lane == 0) { s_redf[wav] = sgt; s_redi[wav] = cgt; }
    __syncthreads();
    if (tid == 0) {
        float s = 0; int cnt = 0;
        for (int w = 0; w < 16; w++) { s += s_redf[w]; cnt += s_redi[w]; }
        float chard = (K > 0u) ? (s + (float)(int)(K - (unsigned)cnt) * __uint_as_float(T)) : 0.0f;
        rstats[(size_t)row * 8 + 4] = chard;
    }
}

// ---------------- Final cross-row reduction ----------------
__global__ void mbox_finalize(const float* __restrict__ rstats, float* __restrict__ out) {
    int c = threadIdx.x;
    float loss = 0.0f;
    if (c < CC) {
        float np = 0, l1 = 0, cp = 0, ch = 0;
        for (int n = 0; n < NN; n++) {
            const float* s = rstats + ((size_t)(n * CC + c)) * 8;
            np += s[0]; l1 += s[1]; cp += s[2]; ch += s[4];
        }
        float loc = l1 / fmaxf(np * 4.0f, 1.0f);
        float val = (np > 0.0f) ? (cp + ch + loc) / fmaxf(np, 1.0f) : 0.0f;
        loss = val / (float)CC;
    }
#pragma unroll
    for (int off = 32; off; off >>= 1) loss += __shfl_down(loss, off);
    if (threadIdx.x == 0) out[0] = loss;
}

extern "C" void kernel_launch(void* const* d_in, const int* in_sizes, int n_in,
                              void* d_out, int out_size, void* d_ws, size_t ws_size,
                              hipStream_t stream) {
    const float* locs   = (const float*)d_in[0];
    const float* scores = (const float*)d_in[1];
    const float* boxes  = (const float*)d_in[2];
    const int*   labels = (const int*)d_in[3];
    const float* priors = (const float*)d_in[4];
    float* out = (float*)d_out;

    float* rstats = (float*)d_ws;   // 160 rows * 8 floats = 5,120 B

    mbox_fused<<<ROWS, FBLK, 0, stream>>>(locs, scores, boxes, labels, priors, rstats);
    mbox_finalize<<<1, 64, 0, stream>>>(rstats, out);
}